// Round 2
// baseline (810.436 us; speedup 1.0000x reference)
//
#include <hip/hip_runtime.h>
#include <hip/hip_bf16.h>

#define N_FILT   80
#define FILT_DIM 251
#define PAD      125
#define SEQ      32000
#define BATCH    32

// fp32 rounding of 2*pi, matching JAX f32 scalar
#define TWO_PI_F 6.28318530717958647692f

// ---------------- Kernel 1: generate the 80x251 filter bank (fp32) ----------
// Replicates _make_filters numerically in fp32 with the reference's multiply
// order:  arg = (two_pi * (f*fs)) * k   (k = |i-125|, exact int)
__global__ void gen_filters(const float* __restrict__ b1p,
                            const float* __restrict__ bandp,
                            float* __restrict__ filt) {
    const int f = blockIdx.x;      // filter index 0..79
    const int i = threadIdx.x;     // tap index 0..255 (251 active)

    const float min_f = 0.003125f; // 50/16000, exact
    float b1   = fabsf(b1p[f]);
    float band = fabsf(bandp[f]);
    float beg  = b1 + min_f;
    float end  = beg + band + min_f;

    float bp = -1e30f;
    if (i < FILT_DIM) {
        int d = i - PAD;
        float lpe, lpb;
        if (d == 0) {
            lpe = 2.0f * end;
            lpb = 2.0f * beg;
        } else {
            float kf = (float)(d < 0 ? -d : d);
            float ae = (TWO_PI_F * (end * 16000.0f)) * kf;
            float ab = (TWO_PI_F * (beg * 16000.0f)) * kf;
            lpe = (2.0f * end) * (sinf(ae) / ae);
            lpb = (2.0f * beg) * (sinf(ab) / ab);
        }
        bp = lpe - lpb;
    }

    // block max-reduce over the 251 band_pass values
    __shared__ float red[256];
    red[i] = bp;
    __syncthreads();
    for (int s = 128; s > 0; s >>= 1) {
        if (i < s) red[i] = fmaxf(red[i], red[i + s]);
        __syncthreads();
    }
    float mx = red[0];

    if (i < FILT_DIM) {
        // n = linspace(0, 251, 251): step = 251/250 in fp32
        float n = (float)i * (251.0f / 250.0f);
        float w = 0.54f - 0.46f * cosf((TWO_PI_F * n) / 251.0f);
        filt[f * FILT_DIM + i] = (bp / mx) * w;
    }
}

// ---------------- Kernel 2: direct conv, fp32 in/out ------------------------
#define BT   256           // threads per block
#define RPT  8             // consecutive outputs per thread
#define TPOS (BT * RPT)    // 2048 output positions per block
#define FG   4             // filters per LDS group
#define XS_LEN (TPOS + FILT_DIM + RPT)  // 2307 staged x values

__global__ __launch_bounds__(BT) void conv_kernel(
        const float* __restrict__ x,
        const float* __restrict__ filt,
        float* __restrict__ out) {
    __shared__ float xs[XS_LEN];
    __shared__ float wl[FG * 256];

    const int tile = blockIdx.x;
    const int b    = blockIdx.y;
    const int tid  = threadIdx.x;
    const int t0   = tile * TPOS;
    const float* xb = x + (size_t)b * SEQ;

    // stage x tile: xs[p] = x[t0 - PAD + p], zero-padded
    for (int p = tid; p < XS_LEN; p += BT) {
        int g = t0 - PAD + p;
        float v = 0.0f;
        if (g >= 0 && g < SEQ) v = xb[g];
        xs[p] = v;
    }

    const int base = tid * RPT;       // position within tile
    const int t    = t0 + base;       // absolute output position

    for (int fg = 0; fg < N_FILT; fg += FG) {
        __syncthreads();  // xs ready (fg=0) / previous group's reads done
        for (int p = tid; p < FG * FILT_DIM; p += BT) {
            int f = p / FILT_DIM;
            int j = p - f * FILT_DIM;
            wl[f * 256 + j] = filt[(fg + f) * FILT_DIM + j];
        }
        __syncthreads();

        float acc[FG][RPT];
        #pragma unroll
        for (int f = 0; f < FG; ++f)
            #pragma unroll
            for (int r = 0; r < RPT; ++r) acc[f][r] = 0.0f;

        float win[RPT];
        #pragma unroll
        for (int r = 0; r < RPT; ++r) win[r] = xs[base + r];

        #pragma unroll 8
        for (int j = 0; j < FILT_DIM; ++j) {
            float w0 = wl[0 * 256 + j];
            float w1 = wl[1 * 256 + j];
            float w2 = wl[2 * 256 + j];
            float w3 = wl[3 * 256 + j];
            #pragma unroll
            for (int r = 0; r < RPT; ++r) {
                acc[0][r] = fmaf(w0, win[r], acc[0][r]);
                acc[1][r] = fmaf(w1, win[r], acc[1][r]);
                acc[2][r] = fmaf(w2, win[r], acc[2][r]);
                acc[3][r] = fmaf(w3, win[r], acc[3][r]);
            }
            #pragma unroll
            for (int r = 0; r < RPT - 1; ++r) win[r] = win[r + 1];
            win[RPT - 1] = xs[base + j + RPT];
        }

        #pragma unroll
        for (int f = 0; f < FG; ++f) {
            size_t o = ((size_t)(b * N_FILT + fg + f)) * SEQ + t;
            if (t + RPT <= SEQ) {
                float4 v0 = make_float4(acc[f][0], acc[f][1], acc[f][2], acc[f][3]);
                float4 v1 = make_float4(acc[f][4], acc[f][5], acc[f][6], acc[f][7]);
                *reinterpret_cast<float4*>(&out[o])     = v0;
                *reinterpret_cast<float4*>(&out[o + 4]) = v1;
            } else {
                for (int r = 0; r < RPT; ++r)
                    if (t + r < SEQ) out[o + r] = acc[f][r];
            }
        }
    }
}

extern "C" void kernel_launch(void* const* d_in, const int* in_sizes, int n_in,
                              void* d_out, int out_size, void* d_ws, size_t ws_size,
                              hipStream_t stream) {
    const float* x    = (const float*)d_in[0];
    const float* b1   = (const float*)d_in[1];
    const float* band = (const float*)d_in[2];
    float* filt = (float*)d_ws;                    // 80*251*4 = 80,320 B scratch
    float* out  = (float*)d_out;

    gen_filters<<<N_FILT, 256, 0, stream>>>(b1, band, filt);

    dim3 grid((SEQ + TPOS - 1) / TPOS, BATCH);     // 16 x 32 = 512 blocks
    conv_kernel<<<grid, BT, 0, stream>>>(x, filt, out);
}

// Round 3
// 371.869 us; speedup vs baseline: 2.1794x; 2.1794x over previous
//
#include <hip/hip_runtime.h>
#include <hip/hip_bf16.h>

#define N_FILT   80
#define FILT_DIM 251
#define PAD      125
#define SEQ      32000
#define BATCH    32
#define TWO_PI_F 6.28318530717958647692f

typedef __attribute__((ext_vector_type(8))) short short8;
typedef __attribute__((ext_vector_type(4))) float floatx4;

// ---------------- Kernel 1: filters -> bf16 A-fragments ---------------------
// Numerics identical to the validated round-2 gen_filters; output is scattered
// into MFMA A-operand fragment order for 16x16x32 bf16:
//   A[m=lane&15][k=(lane>>4)*8+j],  f = 16*ft + m,  k = 32*ks + 8*q + j
// half-index: (((ft*8+ks)*4+q)*16 + m)*8 + j.  K padded 251->256 with zeros.
__global__ void gen_filters(const float* __restrict__ b1p,
                            const float* __restrict__ bandp,
                            unsigned short* __restrict__ afrag) {
    const int f = blockIdx.x;      // filter 0..79
    const int i = threadIdx.x;     // tap 0..255

    const float min_f = 0.003125f; // 50/16000 exact
    float b1   = fabsf(b1p[f]);
    float band = fabsf(bandp[f]);
    float beg  = b1 + min_f;
    float end  = beg + band + min_f;

    float bp = -1e30f;
    if (i < FILT_DIM) {
        int d = i - PAD;
        float lpe, lpb;
        if (d == 0) { lpe = 2.0f*end; lpb = 2.0f*beg; }
        else {
            float kf = (float)(d < 0 ? -d : d);
            float ae = (TWO_PI_F * (end * 16000.0f)) * kf;
            float ab = (TWO_PI_F * (beg * 16000.0f)) * kf;
            lpe = (2.0f*end) * (sinf(ae)/ae);
            lpb = (2.0f*beg) * (sinf(ab)/ab);
        }
        bp = lpe - lpb;
    }

    __shared__ float red[256];
    red[i] = bp;
    __syncthreads();
    for (int s = 128; s > 0; s >>= 1) {
        if (i < s) red[i] = fmaxf(red[i], red[i+s]);
        __syncthreads();
    }
    float mx = red[0];

    float val = 0.0f;
    if (i < FILT_DIM) {
        float n = (float)i * (251.0f/250.0f);
        float w = 0.54f - 0.46f*cosf((TWO_PI_F*n)/251.0f);
        val = (bp/mx) * w;
    }
    __hip_bfloat16 h = __float2bfloat16(val);
    const int ft = f >> 4, m = f & 15;
    const int ks = i >> 5, q = (i >> 3) & 3, j = i & 7;
    afrag[((((ft*8+ks)*4+q)*16) + m)*8 + j] = *reinterpret_cast<unsigned short*>(&h);
}

// ---------------- Kernel 2: implicit-GEMM conv via bf16 MFMA ----------------
// Block: 256 thr (4 waves), tile = 640 positions = 40 pos-tiles = 20 pairs.
// LDS: A-frags 40960 B + 8 shifted bf16 x-copies 8*904*2 = 14464 B -> 55.4 KB.
// Shifted copies make every B-fragment load an aligned ds_read_b128:
//   copy c[m] = x[t0-125 + m + c];  lane needs x[t0-125 + s0 .. s0+8),
//   s0 = 32*pp(+16) + n + 32*ks + 8*q + 8*(n>>3) ... s0 mod 8 == n&7 == c.
#define BLK_POS 640
#define NPAIR   20
#define XS_H    904   // halfword stride/copy; 904*2B: bank phase +4 dw per copy

__global__ __launch_bounds__(256) void conv_mfma(
        const float* __restrict__ x,
        const unsigned short* __restrict__ afrag,
        float* __restrict__ out) {
    __shared__ __align__(16) unsigned short ash[80*256];  // 40960 B
    __shared__ __align__(16) unsigned short xsh[8*XS_H];  // 14464 B

    const int b   = blockIdx.y;
    const int t0  = blockIdx.x * BLK_POS;
    const int tid = threadIdx.x;
    const float* xb = x + (size_t)b * SEQ;

    // A fragments: global -> LDS, 2560 int4
    {
        const int4* src = reinterpret_cast<const int4*>(afrag);
        int4*       dst = reinterpret_cast<int4*>(ash);
        for (int i = tid; i < (80*256)/8; i += 256) dst[i] = src[i];
    }
    // x tile -> 8 shifted bf16 copies (zero-padded outside the sequence)
    for (int c = 0; c < 8; ++c) {
        unsigned short* cp = xsh + c*XS_H;
        for (int m = tid; m < XS_H; m += 256) {
            int g = t0 - PAD + m + c;
            float v = (g >= 0 && g < SEQ) ? xb[g] : 0.0f;
            __hip_bfloat16 h = __float2bfloat16(v);
            cp[m] = *reinterpret_cast<unsigned short*>(&h);
        }
    }
    __syncthreads();

    const int lane = tid & 63;
    const int w    = tid >> 6;
    const int n    = lane & 15;        // MFMA col = position within pos-tile
    const int q    = lane >> 4;        // quad
    const int cc   = n & 7;            // which shifted copy
    const int bbase = cc*XS_H + 8*q + 8*(n>>3);   // + off0 (+16) + 32*ks

    for (int pp = w; pp < NPAIR; pp += 4) {
        const int off0 = 32*pp;        // position offset of pt0 (pt1 = +16)
        short8 B0[8], B1[8];
        #pragma unroll
        for (int ks = 0; ks < 8; ++ks) {
            B0[ks] = *reinterpret_cast<const short8*>(xsh + bbase + off0 + 32*ks);
            B1[ks] = *reinterpret_cast<const short8*>(xsh + bbase + off0 + 16 + 32*ks);
        }
        #pragma unroll
        for (int ft = 0; ft < 5; ++ft) {
            floatx4 a0 = {0.f,0.f,0.f,0.f}, a1 = {0.f,0.f,0.f,0.f};
            #pragma unroll
            for (int ks = 0; ks < 8; ++ks) {
                short8 A = *reinterpret_cast<const short8*>(ash + ((ft*8+ks)*64 + lane)*8);
                a0 = __builtin_amdgcn_mfma_f32_16x16x32_bf16(A, B0[ks], a0, 0, 0, 0);
                a1 = __builtin_amdgcn_mfma_f32_16x16x32_bf16(A, B1[ks], a1, 0, 0, 0);
            }
            // C/D layout: col = lane&15 (position), row = q*4 + r (filter)
            size_t obase = ((size_t)(b*N_FILT + ft*16 + 4*q))*SEQ + t0 + off0 + n;
            #pragma unroll
            for (int r = 0; r < 4; ++r) {
                out[obase + (size_t)r*SEQ]      = a0[r];
                out[obase + (size_t)r*SEQ + 16] = a1[r];
            }
        }
    }
}

extern "C" void kernel_launch(void* const* d_in, const int* in_sizes, int n_in,
                              void* d_out, int out_size, void* d_ws, size_t ws_size,
                              hipStream_t stream) {
    const float* x    = (const float*)d_in[0];
    const float* b1   = (const float*)d_in[1];
    const float* band = (const float*)d_in[2];
    unsigned short* afrag = (unsigned short*)d_ws;   // 80*256*2 = 40960 B
    float* out = (float*)d_out;

    gen_filters<<<N_FILT, 256, 0, stream>>>(b1, band, afrag);

    dim3 grid(SEQ / BLK_POS, BATCH);                 // 50 x 32 = 1600 blocks
    conv_mfma<<<grid, 256, 0, stream>>>(x, afrag, out);
}